// Round 7
// baseline (490.314 us; speedup 1.0000x reference)
//
#include <hip/hip_runtime.h>

// SelfAttention: B=8, C=512, T=2048, Cq=64. fp32 in/out, bf16 MFMA inside.
// out[b,c,t] = gamma * (softmax(Q K^T) V)[t,c] + x[b,c,t]
//
// Buffers:
//   d_out: xT [B][T][C] bf16 @0 (16.78 MB) | Wb bf16 (wq|wk|wv) @17 MiB (640 KB)
//          (both dead before k_attn, which fully overwrites d_out)
//   ws:    QK [B][T][128] bf16 @0 (4 MiB) | VT [B][C][T] bf16 @4 MiB (16 MiB)
//
// Flat-grid XCD swizzle everywhere: b = blockIdx.x & 7 -> per-XCD L2 keeps
// QK[b] (0.5 MB) + VT[b] (2 MB) resident (round-6 evidence: FETCH 92->27 MB).
//
// k_attn v3: NO LDS in the loop. S^T via MFMA operand swap (A/B frag lane maps
// are identical), P C-layout -> B-operand via pack+ds_bpermute (in-register),
// K/V frags direct from L2 with 1-iter register double-buffer (vmcnt(12)
// pipeline), zero barriers.

#define B_ 8
#define C_ 512
#define T_ 2048

typedef __attribute__((ext_vector_type(4))) float f32x4;
typedef __attribute__((ext_vector_type(8))) short bf16x8;
typedef unsigned short u16;
typedef unsigned int u32;

__device__ __forceinline__ u16 f2bf(float f) {
  u32 u = __float_as_uint(f);
  u += 0x7fffu + ((u >> 16) & 1);   // RNE
  return (u16)(u >> 16);
}
__device__ __forceinline__ float bf2f(u16 h) {
  return __uint_as_float(((u32)h) << 16);
}

// ---------------- kernel 0: weights fp32 -> bf16 (wq|wk|wv concat)
extern "C" __global__ __launch_bounds__(256)
void k_wcvt(const float* __restrict__ wq, const float* __restrict__ wk,
            const float* __restrict__ wv, u16* __restrict__ W) {
  int i = blockIdx.x * 256 + threadIdx.x;        // float4 index, total 81920
  const float* src; u16* dst;
  if (i < 8192)       { src = wq + (size_t)i * 4;            dst = W + (size_t)i * 4; }
  else if (i < 16384) { int j = i - 8192;  src = wk + (size_t)j * 4; dst = W + 32768 + (size_t)j * 4; }
  else                { int j = i - 16384; src = wv + (size_t)j * 4; dst = W + 65536 + (size_t)j * 4; }
  float4 f = *(const float4*)src;
  ushort4 o;
  o.x = f2bf(f.x); o.y = f2bf(f.y); o.z = f2bf(f.z); o.w = f2bf(f.w);
  *(ushort4*)dst = o;
}

// ---------------- kernel 1: x [B][C][T] fp32 -> xT [B][T][C] bf16
extern "C" __global__ __launch_bounds__(256)
void k_xpose(const float* __restrict__ x, u16* __restrict__ xT) {
  __shared__ alignas(16) u16 lds[64 * 72];
  const int tid = threadIdx.x;
  const int t0 = blockIdx.x * 64;
  const int c0 = blockIdx.y * 64;
  const int b  = blockIdx.z;
  const int cr = tid >> 2, tq = tid & 3;
  const float* xp = x + ((size_t)(b * C_ + c0 + cr)) * T_ + t0 + tq * 16;
  u16 vals[16];
#pragma unroll
  for (int q = 0; q < 4; q++) {
    float4 f = *(const float4*)(xp + q * 4);
    vals[q * 4 + 0] = f2bf(f.x);
    vals[q * 4 + 1] = f2bf(f.y);
    vals[q * 4 + 2] = f2bf(f.z);
    vals[q * 4 + 3] = f2bf(f.w);
  }
#pragma unroll
  for (int j = 0; j < 16; j++) lds[(tq * 16 + j) * 72 + cr] = vals[j];
  __syncthreads();
  const int tr = tid >> 2, cq = tid & 3;
  uint4 oa = *(const uint4*)&lds[tr * 72 + cq * 16];
  uint4 ob = *(const uint4*)&lds[tr * 72 + cq * 16 + 8];
  u16* op = xT + ((size_t)(b * T_ + t0 + tr)) * C_ + c0 + cq * 16;
  *(uint4*)op = oa;
  *(uint4*)(op + 8) = ob;
}

// ---------------- kernel 2: QK = [xT*wq^T | xT*wk^T] + bias -> [B][T][128]
extern "C" __global__ __launch_bounds__(256)
void k_qk(const u16* __restrict__ xT, const u16* __restrict__ W,
          const float* __restrict__ bq, const float* __restrict__ bk,
          u16* __restrict__ QK) {
  const int tid = threadIdx.x;
  const int wave = tid >> 6, lane = tid & 63;
  const int quad = lane >> 4, l15 = lane & 15;
  const int id = blockIdx.x;
  const int b  = id & 7;
  const int t0 = (id >> 3) * 32;
  const int n0 = wave * 32;
  f32x4 acc[2][2];
#pragma unroll
  for (int i = 0; i < 2; i++)
#pragma unroll
    for (int j = 0; j < 2; j++) acc[i][j] = (f32x4){0.f, 0.f, 0.f, 0.f};
#pragma unroll
  for (int ks = 0; ks < 16; ks++) {
    bf16x8 af[2], bf[2];
#pragma unroll
    for (int mt = 0; mt < 2; mt++)
      af[mt] = *(const bf16x8*)(xT + ((size_t)(b * T_ + t0 + mt * 16 + l15)) * C_ +
                                ks * 32 + quad * 8);
#pragma unroll
    for (int ntl = 0; ntl < 2; ntl++) {
      const int n = n0 + ntl * 16 + l15;
      const u16* wrow = (n < 64) ? (W + (size_t)n * C_)
                                 : (W + 32768 + (size_t)(n - 64) * C_);
      bf[ntl] = *(const bf16x8*)(wrow + ks * 32 + quad * 8);
    }
#pragma unroll
    for (int mt = 0; mt < 2; mt++)
#pragma unroll
      for (int ntl = 0; ntl < 2; ntl++)
        acc[mt][ntl] = __builtin_amdgcn_mfma_f32_16x16x32_bf16(af[mt], bf[ntl],
                                                               acc[mt][ntl], 0, 0, 0);
  }
#pragma unroll
  for (int ntl = 0; ntl < 2; ntl++) {
    const int n = n0 + ntl * 16 + l15;
    const float bias = (n < 64) ? bq[n] : bk[n - 64];
#pragma unroll
    for (int mt = 0; mt < 2; mt++)
#pragma unroll
      for (int r = 0; r < 4; r++) {
        const int t = t0 + mt * 16 + quad * 4 + r;
        QK[((size_t)(b * T_ + t)) * 128 + n] = f2bf(acc[mt][ntl][r] + bias);
      }
  }
}

// ---------------- kernel 3: VT[b][c][t] = (wv . x[b][:,t])_c + bv[c]
extern "C" __global__ __launch_bounds__(256)
void k_vt(const u16* __restrict__ xT, const u16* __restrict__ Wv,
          const float* __restrict__ bv, u16* __restrict__ VT) {
  const int tid = threadIdx.x;
  const int wave = tid >> 6, lane = tid & 63;
  const int quad = lane >> 4, l15 = lane & 15;
  const int id = blockIdx.x;
  const int b   = id & 7;
  const int slot = id >> 3;
  const int tt0 = (slot & 15) * 128;
  const int c00 = (slot >> 4) * 128;
  const int wm = (wave >> 1) * 64, wn = (wave & 1) * 64;
  f32x4 acc[4][4];
#pragma unroll
  for (int i = 0; i < 4; i++)
#pragma unroll
    for (int j = 0; j < 4; j++) acc[i][j] = (f32x4){0.f, 0.f, 0.f, 0.f};

  bf16x8 af[2][4], bfr[2][4];
  auto ldst = [&](int ks, int s) {
#pragma unroll
    for (int mt = 0; mt < 4; mt++)
      af[s][mt] = *(const bf16x8*)(Wv + ((size_t)(c00 + wm + mt * 16 + l15)) * C_ +
                                   ks * 32 + quad * 8);
#pragma unroll
    for (int nt = 0; nt < 4; nt++)
      bfr[s][nt] = *(const bf16x8*)(xT + ((size_t)(b * T_ + tt0 + wn + nt * 16 + l15)) * C_ +
                                    ks * 32 + quad * 8);
  };
  ldst(0, 0);
#pragma unroll
  for (int ks = 0; ks < 16; ks++) {
    const int cur = ks & 1;
    if (ks < 15) ldst(ks + 1, cur ^ 1);
#pragma unroll
    for (int mt = 0; mt < 4; mt++)
#pragma unroll
      for (int nt = 0; nt < 4; nt++)
        acc[mt][nt] = __builtin_amdgcn_mfma_f32_16x16x32_bf16(af[cur][mt], bfr[cur][nt],
                                                              acc[mt][nt], 0, 0, 0);
  }
#pragma unroll
  for (int mt = 0; mt < 4; mt++) {
#pragma unroll
    for (int r = 0; r < 4; r++) {
      const int c = c00 + wm + mt * 16 + quad * 4 + r;
      const float bias = bv[c];
#pragma unroll
      for (int nt = 0; nt < 4; nt++) {
        const int t = tt0 + wn + nt * 16 + l15;
        VT[((size_t)(b * C_ + c)) * T_ + t] = f2bf(acc[mt][nt][r] + bias);
      }
    }
  }
}

// ---------------- kernel 4: fused attention, no LDS, no barriers
// flat grid 512: b = id&7, slot: c-half = slot>>5, t-tile = slot&31.
// 4 waves; wave owns 128 c x 32 t, computes S^T (operand swap) so P reaches
// the PV B-operand via pack + ds_bpermute. K/V frags: L2-direct, reg dbuf.
extern "C" __global__ __launch_bounds__(256)
void k_attn(const u16* __restrict__ QK, const u16* __restrict__ VT,
            const float* __restrict__ x, const float* __restrict__ gamma,
            float* __restrict__ out) {
  const int tid = threadIdx.x;
  const int wave = tid >> 6, lane = tid & 63;
  const int quad = lane >> 4, l15 = lane & 15;
  const int id = blockIdx.x;
  const int b  = id & 7;
  const int slot = id >> 3;
  const int c0 = (slot >> 5) * 256;
  const int t0 = (slot & 31) * 64;
  const int wt = wave & 1;        // t-half (32 rows)
  const int wc = wave >> 1;       // c-half (128 cols)
  const float g = gamma[0];

  // Q as B-operand frags (lane l15 = t, k = c) — same data as an A-frag load
  bf16x8 qa[2][2];
#pragma unroll
  for (int tt = 0; tt < 2; tt++) {
    const u16* qp = QK + ((size_t)(b * T_ + t0 + wt * 32 + tt * 16 + l15)) * 128 + quad * 8;
    qa[tt][0] = *(const bf16x8*)qp;
    qa[tt][1] = *(const bf16x8*)(qp + 32);
  }

  // O^T accumulators: acc[ct][tt], D[m=c][n=t]: c = ct*16+quad*4+r, t = tt*16+l15
  f32x4 acc[8][2];
#pragma unroll
  for (int i = 0; i < 8; i++)
#pragma unroll
    for (int j = 0; j < 2; j++) acc[i][j] = (f32x4){0.f, 0.f, 0.f, 0.f};
  float lacc[2] = {0.f, 0.f};

  const u16* kbase = QK + (size_t)b * T_ * 128 + 64;
  const u16* vbase = VT + ((size_t)(b * C_ + c0 + wc * 128)) * T_;

  bf16x8 kf[2][2][2];   // [buf][st][ks]: K A-frag, lane l15 = s, k = c
  bf16x8 vf[2][8];      // [buf][ct]:     V^T A-frag, lane l15 = c, k = s

  auto ld_tiles = [&](int s0, int buf) {
#pragma unroll
    for (int st = 0; st < 2; st++)
#pragma unroll
      for (int ks = 0; ks < 2; ks++)
        kf[buf][st][ks] = *(const bf16x8*)(kbase + ((size_t)(s0 + st * 16 + l15)) * 128 +
                                           ks * 32 + quad * 8);
#pragma unroll
    for (int ct = 0; ct < 8; ct++)
      vf[buf][ct] = *(const bf16x8*)(vbase + ((size_t)(ct * 16 + l15)) * T_ +
                                     s0 + quad * 8);
  };

  const int srcb = (quad & 1) * 32 + l15;   // bpermute src base: quad'=2(quad&1)+m

  auto body = [&](int cur) {
    // S^T = K Q^T (operand swap): D[m=s][n=t]; lane: s = quad*4+r, t = l15
    f32x4 sa[2][2];
#pragma unroll
    for (int st = 0; st < 2; st++)
#pragma unroll
      for (int tt = 0; tt < 2; tt++) sa[st][tt] = (f32x4){0.f, 0.f, 0.f, 0.f};
#pragma unroll
    for (int st = 0; st < 2; st++)
#pragma unroll
      for (int ks = 0; ks < 2; ks++)
#pragma unroll
        for (int tt = 0; tt < 2; tt++)
          sa[st][tt] = __builtin_amdgcn_mfma_f32_16x16x32_bf16(kf[cur][st][ks],
                                                               qa[tt][ks], sa[st][tt], 0, 0, 0);
    // exp + pack bf16 pairs (pair p holds s-locals 2p, 2p+1 of this lane)
    u32 pk[2][2][2];
#pragma unroll
    for (int st = 0; st < 2; st++)
#pragma unroll
      for (int tt = 0; tt < 2; tt++) {
        float e0 = __expf(sa[st][tt][0]);
        float e1 = __expf(sa[st][tt][1]);
        float e2 = __expf(sa[st][tt][2]);
        float e3 = __expf(sa[st][tt][3]);
        lacc[tt] += (e0 + e1) + (e2 + e3);
        pk[st][tt][0] = (u32)f2bf(e0) | ((u32)f2bf(e1) << 16);
        pk[st][tt][1] = (u32)f2bf(e2) | ((u32)f2bf(e3) << 16);
      }
    // P^T B-frags via bpermute: reg w needs src lane (2(quad&1)+(w>>1))*16+l15,
    // value pk[st = quad>>1][tt][w&1] (two shfl variants + select on quad).
#pragma unroll
    for (int tt = 0; tt < 2; tt++) {
      union { u32 u[4]; bf16x8 h; } pb;
#pragma unroll
      for (int w = 0; w < 4; w++) {
        const int src = srcb + (w >> 1) * 16;
        u32 a0 = (u32)__shfl((int)pk[0][tt][w & 1], src);
        u32 a1 = (u32)__shfl((int)pk[1][tt][w & 1], src);
        pb.u[w] = (quad < 2) ? a0 : a1;
      }
#pragma unroll
      for (int ct = 0; ct < 8; ct++)
        acc[ct][tt] = __builtin_amdgcn_mfma_f32_16x16x32_bf16(vf[cur][ct], pb.h,
                                                              acc[ct][tt], 0, 0, 0);
    }
  };

  ld_tiles(0, 0);
#pragma unroll 2
  for (int i = 0; i < 63; i++) {
    ld_tiles((i + 1) * 32, (i & 1) ^ 1);   // vmcnt(12)-style pipeline
    body(i & 1);
  }
  body(1);

  // l[t]: reduce quad-partials (lane t = l15 preserved), then scale factor
#pragma unroll
  for (int tt = 0; tt < 2; tt++) {
    float v = lacc[tt];
    v += __shfl_xor(v, 16);
    v += __shfl_xor(v, 32);
    lacc[tt] = g / v;
  }

  // epilogue: O^T layout -> 16 lanes write 64B-contiguous t-runs
#pragma unroll
  for (int ct = 0; ct < 8; ct++)
#pragma unroll
    for (int tt = 0; tt < 2; tt++)
#pragma unroll
      for (int r = 0; r < 4; r++) {
        const int c = c0 + wc * 128 + ct * 16 + quad * 4 + r;
        const int t = t0 + wt * 32 + tt * 16 + l15;
        const size_t idx = ((size_t)(b * C_ + c)) * T_ + t;
        out[idx] = acc[ct][tt][r] * lacc[tt] + x[idx];
      }
}

extern "C" void kernel_launch(void* const* d_in, const int* in_sizes, int n_in,
                              void* d_out, int out_size, void* d_ws, size_t ws_size,
                              hipStream_t stream) {
  (void)in_sizes; (void)n_in; (void)out_size; (void)ws_size;
  const float* x  = (const float*)d_in[0];
  const float* wq = (const float*)d_in[1];
  const float* bq = (const float*)d_in[2];
  const float* wk = (const float*)d_in[3];
  const float* bk = (const float*)d_in[4];
  const float* wv = (const float*)d_in[5];
  const float* bv = (const float*)d_in[6];
  const float* gm = (const float*)d_in[7];
  float* out = (float*)d_out;

  // d_out scratch: xT @0 (16.78 MB), bf16 weights @17 MiB (640 KB).
  u16* xT = (u16*)d_out;
  u16* Wb = (u16*)((char*)d_out + (size_t)17 * 1024 * 1024);
  char* ws = (char*)d_ws;
  u16* QK = (u16*)ws;                                  //  4 MiB
  u16* VT = (u16*)(ws + (size_t)4 * 1024 * 1024);      // 16 MiB

  k_wcvt<<<320, 256, 0, stream>>>(wq, wk, wv, Wb);
  k_xpose<<<dim3(32, 8, 8), 256, 0, stream>>>(x, xT);
  k_qk  <<<512, 256, 0, stream>>>(xT, Wb, bq, bk, QK);
  k_vt  <<<512, 256, 0, stream>>>(xT, Wb + 65536, bv, VT);
  k_attn<<<512, 256, 0, stream>>>(QK, VT, x, gm, out);
}